// Round 9
// baseline (210.360 us; speedup 1.0000x reference)
//
#include <hip/hip_runtime.h>
#include <math.h>

// VQ-VAE VectorQuantizer forward — single fused kernel (fp16 MFMA + LDS codebook).
//   x: [64,32,32,64] f32 -> N=65536 points, D=64
//   E: [D=64, K=1024] f32 (row-major: E[d*K + k])
// Outputs concatenated flat (float32):
//   quantized_st [N*D] | loss [1] | perplexity [1] | encoding_indices [N] (as float)
//
// dist_fast = ||e_k||^2 + BIAS - 2 f.e_k via MFMA f16. Codebook staged in LDS
// (4 chunks x 256 codes, pre-swizzled image => linear coalesced staging +
// conflict-free ds_read_b128). Index packed in low 8 mantissa bits; shuffle
// cross-quad merge; gated points re-resolved with the round-3-proven exact
// emulation of the np reference's fp32 arithmetic — now reading Et rows
// (contiguous, bit-identical values) instead of 4KB-stride E gathers (r8's
// dominant stall: 512 scalar gathers/lane at VGPR=52). launch_bounds(256,2)
// frees VGPRs for in-flight loads AND guarantees 2 blocks/CU co-residency,
// which makes the fused-prep ready-spin deadlock-free (512 blocks, dispatch
// in ID order, prep blocks 0..63 resident first).

typedef __attribute__((ext_vector_type(8))) _Float16 half8v;
typedef __attribute__((ext_vector_type(4))) float float4v;
typedef unsigned short u16;
typedef unsigned int u32;

constexpr int D = 64;
constexpr int K = 1024;
constexpr int NPTS = 65536;
constexpr long QOFF = (long)NPTS * D;  // 4194304
constexpr float BIAS = 24.0f;          // dist+BIAS ~[3,48]: positive, pack-safe
constexpr float GATE = 2e-2f;          // fp16 5sigma + pack err + margin (r6-r8 proven)
constexpr int GRID = 512;              // 128 points/block; 2 blocks/CU co-resident
constexpr int CHUNK = 256;             // codes per LDS chunk
constexpr int PREP_BLOCKS = 64;

// ws layout: [loss 8][done 4][ready 4][counts 4096] = 4112 zeroed bytes, then:
constexpr size_t OFF_LOSS = 0;
constexpr size_t OFF_DONE = 8;
constexpr size_t OFF_READY = 12;
constexpr size_t OFF_CNT = 16;
constexpr size_t WS_ZERO = 4112;
constexpr size_t OFF_EC = 4352;                           // float[1024] ref-order norms
constexpr size_t OFF_ECB = 8448;                          // float[1024] norms + BIAS
constexpr size_t OFF_ET = 12544;                          // float[1024*64] E^T [k][d]
constexpr size_t OFF_H16 = OFF_ET + (size_t)K * D * 4;    // _Float16[1024*64] swizzled -2E

__device__ __forceinline__ float med3(float a, float b, float c) {
  return __builtin_amdgcn_fmed3f(a, b, c);
}

__global__ __launch_bounds__(256, 2) void vq_fused(const float* __restrict__ x,
                                                   const float* __restrict__ E,
                                                   _Float16* __restrict__ h16,
                                                   float* __restrict__ eC,
                                                   float* __restrict__ eCbG,
                                                   float* __restrict__ Etg,
                                                   float* __restrict__ out,
                                                   double* __restrict__ lossSum,
                                                   int* __restrict__ counts,
                                                   int* __restrict__ done,
                                                   int* __restrict__ ready) {
  __shared__ __align__(16) u16 Abuf[CHUNK * 64];   // 32 KB, swizzled rows
  __shared__ __align__(16) float eCbL[CHUNK];
  __shared__ int bkbuf[128];
  __shared__ double shred[256];
  __shared__ int lastFlag;

  const int tid = threadIdx.x;
  const int w = tid >> 6;        // wave id: owns points w*32 .. w*32+31
  const int lane = tid & 63;
  const int col = lane & 15;     // A: code row m; B/C: point col n
  const int quad = lane >> 4;    // A/B: k-group; C: row-group
  const int blockBase = blockIdx.x * 128;
  const float INF = __builtin_inff();

  // ---- phase 0: blocks 0..63 build Et / swizzled h16 / ref-order norms ----
  if (blockIdx.x < PREP_BLOCKS) {
    const int gid = blockIdx.x * 256 + tid;  // 16384 prep threads
    const int d = gid >> 8;
    const int k0 = (gid & 255) * 4;
    const int dg = d >> 3, dj = d & 7;
    float4 v = *(const float4*)&E[d * K + k0];  // coalesced
#pragma unroll
    for (int i = 0; i < 4; ++i) {
      int k = k0 + i;
      float e = (i == 0) ? v.x : (i == 1) ? v.y : (i == 2) ? v.z : v.w;
      Etg[(size_t)k * 64 + d] = e;
      h16[(size_t)k * 64 + ((dg + k) & 7) * 8 + dj] = (_Float16)(-2.0f * e);
    }
    if (gid < K) {
      // np.sum(E**2, axis=0): sequential fp32 over d ascending (r3-proven)
      float c = __fmul_rn(E[gid], E[gid]);
#pragma unroll
      for (int dd = 1; dd < D; ++dd) {
        float e = E[dd * K + gid];
        c = __fadd_rn(c, __fmul_rn(e, e));
      }
      eC[gid] = c;
      eCbG[gid] = c + BIAS;
    }
    __threadfence();   // flush this thread's global writes to device scope
    __syncthreads();
    if (tid == 0)
      __hip_atomic_fetch_add(ready, 1, __ATOMIC_RELEASE, __HIP_MEMORY_SCOPE_AGENT);
  }

  // ---- phase 1: load + convert x into fp16 B-fragments (overlaps prep) ----
  // B[k = s*32 + quad*8 + j][n = col], frag element j <-> d = s*32+quad*8+j.
  half8v Bf[2][2];
#pragma unroll
  for (int pt = 0; pt < 2; ++pt) {
    const float* xp = x + (size_t)(blockBase + w * 32 + pt * 16 + col) * 64;
#pragma unroll
    for (int s = 0; s < 2; ++s) {
      const float4* src = (const float4*)(xp + s * 32 + quad * 8);
      float4 a = src[0], b = src[1];
      half8v hf;
      hf[0] = (_Float16)a.x; hf[1] = (_Float16)a.y;
      hf[2] = (_Float16)a.z; hf[3] = (_Float16)a.w;
      hf[4] = (_Float16)b.x; hf[5] = (_Float16)b.y;
      hf[6] = (_Float16)b.z; hf[7] = (_Float16)b.w;
      Bf[pt][s] = hf;
    }
  }

  // ---- wait for prep completion (device-scope acquire; co-residency proven) ----
  if (tid == 0) {
    while (__hip_atomic_load(ready, __ATOMIC_ACQUIRE, __HIP_MEMORY_SCOPE_AGENT) <
           PREP_BLOCKS)
      __builtin_amdgcn_s_sleep(2);
  }
  __syncthreads();

  // running top-2 of packed biased distances, per point-tile
  float b1[2] = {INF, INF}, b2[2] = {INF, INF};

  // tile-invariant swizzle offsets (16 = 0 mod 8 => depend only on quad+col)
  const int swz0 = ((quad + col) & 7) * 8;
  const int swz1 = ((quad + 4 + col) & 7) * 8;

  // ---- phase 2: K loop, 4 LDS chunks of 256 codes ----
  for (int ch = 0; ch < 4; ++ch) {
    __syncthreads();  // protect Abuf reuse
    const float4* src = (const float4*)(h16 + (size_t)ch * CHUNK * 64);
#pragma unroll
    for (int r = 0; r < 8; ++r) {
      int idx = r * 256 + tid;
      *(float4*)&Abuf[idx * 8] = src[idx];  // linear coalesced (pre-swizzled)
    }
    if (tid < 64) *(float4*)&eCbL[tid * 4] = *(const float4*)&eCbG[ch * CHUNK + tid * 4];
    __syncthreads();

#pragma unroll
    for (int ct = 0; ct < 16; ++ct) {  // 16 code-tiles of 16
      const u16* arow = &Abuf[(ct * 16 + col) * 64];
      half8v A0 = *(const half8v*)&arow[swz0];
      half8v A1 = *(const half8v*)&arow[swz1];
      float4v Ci = *(const float4v*)&eCbL[ct * 16 + quad * 4];
      const int t = ch * 16 + ct;
#pragma unroll
      for (int pt = 0; pt < 2; ++pt) {
        float4v C = Ci;
        C = __builtin_amdgcn_mfma_f32_16x16x32_f16(A0, Bf[pt][0], C, 0, 0, 0);
        C = __builtin_amdgcn_mfma_f32_16x16x32_f16(A1, Bf[pt][1], C, 0, 0, 0);
#pragma unroll
        for (int r = 0; r < 4; ++r) {
          // pack local id (t:6b | r:2b) into low 8 mantissa bits
          u32 u = (__float_as_uint(C[r]) & 0xffffff00u) | (u32)(t * 4 + r);
          float v = __uint_as_float(u);
          b2[pt] = med3(b1[pt], b2[pt], v);  // old b1 -> correct new second
          b1[pt] = fminf(b1[pt], v);
        }
      }
    }
  }

  // ---- phase 3: shuffle merge across quads; lanes 0..31 own one point each ----
  float sv[8];
  {
    const int scol = lane & 15;
#pragma unroll
    for (int P = 0; P < 2; ++P) {
      float v1 = b1[P], v2 = b2[P];
#pragma unroll
      for (int q = 0; q < 4; ++q) {
        float s1 = __shfl(v1, scol + 16 * q, 64);
        float s2 = __shfl(v2, scol + 16 * q, 64);
        if ((lane >> 4) == P) { sv[q] = s1; sv[4 + q] = s2; }
      }
    }
  }

  if (lane < 32) {
    float m1 = INF, m2 = INF;
#pragma unroll
    for (int j = 0; j < 8; ++j) {
      m2 = med3(m1, m2, sv[j]);
      m1 = fminf(m1, sv[j]);
    }
    int qwin = 0;
#pragma unroll
    for (int j = 0; j < 8; ++j)
      if (__float_as_uint(sv[j]) == __float_as_uint(m1)) qwin = j & 3;
    u32 lb = __float_as_uint(m1) & 255u;
    int bestk = (int)((lb >> 2) * 16 + qwin * 4 + (lb & 3));
    const int myPoint = blockBase + w * 32 + lane;

    if (m2 - m1 < GATE) {
      // ----- exact emulation of the np reference's fp32 arithmetic -----
      // Reads Et rows (contiguous, bit-identical to E columns) — r8's stall
      // was the 4KB-stride E gather here.
      const float4* fx = (const float4*)(x + (size_t)myPoint * 64);
      float fr[64];
#pragma unroll
      for (int i = 0; i < 16; ++i) {
        float4 v = fx[i];
        fr[4 * i + 0] = v.x; fr[4 * i + 1] = v.y;
        fr[4 * i + 2] = v.z; fr[4 * i + 3] = v.w;
      }
      // A = np.sum(f**2) (pairwise-8 pattern)
      float r8v[8];
#pragma unroll
      for (int j = 0; j < 8; ++j) r8v[j] = __fmul_rn(fr[j], fr[j]);
#pragma unroll
      for (int i = 8; i < D; i += 8)
#pragma unroll
        for (int j = 0; j < 8; ++j)
          r8v[j] = __fadd_rn(r8v[j], __fmul_rn(fr[i + j], fr[i + j]));
      float A = __fadd_rn(__fadd_rn(__fadd_rn(r8v[0], r8v[1]), __fadd_rn(r8v[2], r8v[3])),
                          __fadd_rn(__fadd_rn(r8v[4], r8v[5]), __fadd_rn(r8v[6], r8v[7])));
      // 8 distinct candidates; independent m-chains, sequential-over-d order.
      int kk[8];
      float mm[8];
      const float4* rowp[8];
#pragma unroll
      for (int c = 0; c < 8; ++c) {
        u32 cb = __float_as_uint(sv[c]) & 255u;
        kk[c] = (int)((cb >> 2) * 16 + (c & 3) * 4 + (cb & 3));
        mm[c] = 0.f;
        rowp[c] = (const float4*)(Etg + (size_t)kk[c] * 64);
      }
#pragma unroll 4
      for (int i = 0; i < 16; ++i) {
#pragma unroll
        for (int c = 0; c < 8; ++c) {
          float4 e = rowp[c][i];
          float m = mm[c];
          m = __fmaf_rn(fr[4 * i + 0], e.x, m);
          m = __fmaf_rn(fr[4 * i + 1], e.y, m);
          m = __fmaf_rn(fr[4 * i + 2], e.z, m);
          m = __fmaf_rn(fr[4 * i + 3], e.w, m);
          mm[c] = m;
        }
      }
      float bd = INF;
      int bkk = K;
#pragma unroll
      for (int c = 0; c < 8; ++c) {
        float dist = __fadd_rn(__fsub_rn(A, __fmul_rn(2.f, mm[c])), eC[kk[c]]);
        bool better = (dist < bd) || (dist == bd && kk[c] < bkk);
        bd = better ? dist : bd;
        bkk = better ? kk[c] : bkk;
      }
      bestk = bkk;
    }

    bkbuf[w * 32 + lane] = bestk;
    out[QOFF + 2 + myPoint] = (float)bestk;  // index (exact as float)
    atomicAdd(&counts[bestk], 1);
  }
  __syncthreads();

  // ---- phase 4: quantized write (gather from Et, coalesced) + loss ----
  const int pp = tid >> 1, half = tid & 1;
  const int bk = bkbuf[pp];
  const float4* et = (const float4*)(Etg + (size_t)bk * 64 + half * 32);
  const float4* xr = (const float4*)(x + (size_t)(blockBase + pp) * 64 + half * 32);
  float4* ov = (float4*)(out + (size_t)(blockBase + pp) * 64 + half * 32);
  float errs = 0.f;
#pragma unroll
  for (int i = 0; i < 8; ++i) {
    float4 qv = et[i];
    float4 xv = xr[i];
    float dx;
    dx = qv.x - xv.x; errs = fmaf(dx, dx, errs);
    dx = qv.y - xv.y; errs = fmaf(dx, dx, errs);
    dx = qv.z - xv.z; errs = fmaf(dx, dx, errs);
    dx = qv.w - xv.w; errs = fmaf(dx, dx, errs);
    ov[i] = qv;
  }
  double de = (double)errs;
#pragma unroll
  for (int off = 32; off > 0; off >>= 1) de += __shfl_down(de, off, 64);
  if (lane == 0) atomicAdd(lossSum, de);

  // ---- phase 5: last block finalizes loss + perplexity ----
  __syncthreads();
  if (tid == 0) {
    int old = __hip_atomic_fetch_add(done, 1, __ATOMIC_ACQ_REL,
                                     __HIP_MEMORY_SCOPE_AGENT);
    lastFlag = (old == GRID - 1);
  }
  __syncthreads();
  if (lastFlag) {
    double ent = 0.0;
    for (int k = tid; k < K; k += 256) {
      int c = __hip_atomic_load(&counts[k], __ATOMIC_RELAXED,
                                __HIP_MEMORY_SCOPE_AGENT);
      double pp2 = (double)c / (double)NPTS;
      ent += pp2 * log(pp2 + 1e-10);
    }
    shred[tid] = ent;
    __syncthreads();
    for (int s = 128; s > 0; s >>= 1) {
      if (tid < s) shred[tid] += shred[tid + s];
      __syncthreads();
    }
    if (tid == 0) {
      double ls = __hip_atomic_load(lossSum, __ATOMIC_RELAXED,
                                    __HIP_MEMORY_SCOPE_AGENT);
      // loss = q_latent + 0.25 * e_latent = 1.25 * mean((q - x)^2)
      out[QOFF + 0] = (float)(1.25 * ls / (double)((long)NPTS * D));
      out[QOFF + 1] = (float)exp(-shred[0]);  // perplexity
    }
  }
}

extern "C" void kernel_launch(void* const* d_in, const int* in_sizes, int n_in,
                              void* d_out, int out_size, void* d_ws, size_t ws_size,
                              hipStream_t stream) {
  const float* x = (const float*)d_in[0];
  const float* E = (const float*)d_in[1];
  float* out = (float*)d_out;

  char* ws = (char*)d_ws;
  double* lossSum = (double*)(ws + OFF_LOSS);
  int* done = (int*)(ws + OFF_DONE);
  int* ready = (int*)(ws + OFF_READY);
  int* counts = (int*)(ws + OFF_CNT);
  float* eC = (float*)(ws + OFF_EC);
  float* eCb = (float*)(ws + OFF_ECB);
  float* Etg = (float*)(ws + OFF_ET);
  _Float16* h16 = (_Float16*)(ws + OFF_H16);

  // zero accumulators + flags (ws is 0xAA-poisoned before every timed launch)
  hipMemsetAsync(d_ws, 0, WS_ZERO, stream);
  vq_fused<<<GRID, 256, 0, stream>>>(x, E, h16, eC, eCb, Etg, out, lossSum,
                                     counts, done, ready);
}

// Round 10
// 142.617 us; speedup vs baseline: 1.4750x; 1.4750x over previous
//
#include <hip/hip_runtime.h>
#include <math.h>

// VQ-VAE VectorQuantizer forward — round-5 MFMA core (67us measured, best) +
// two proven deltas: fused finalize (r8's done-counter, no fence) and a single
// fused prep dispatch. Refinement reads Et rows (bit-identical, r9-proven).
//   x: [64,32,32,64] f32 -> N=65536 points, D=64
//   E: [D=64, K=1024] f32 (row-major: E[d*K + k])
// Outputs concatenated flat (float32):
//   quantized_st [N*D] | loss [1] | perplexity [1] | encoding_indices [N] (as float)
//
// dist_fast = ||e_k||^2 + BIAS - 2 f.e_k via bf16 hi/lo split MFMA
// (3 products, abs err ~5e-4). Per-(lane,pt) top-2 of packed biased dists
// (index in low 8 mantissa bits). LDS merge -> 8 candidates/point; gated
// points (gap < GATE) re-resolved with the round-3-proven exact emulation of
// the np reference's fp32 arithmetic (first-occurrence ties).

typedef __attribute__((ext_vector_type(8))) short short8v;
typedef __attribute__((ext_vector_type(4))) float float4v;
typedef unsigned short u16;
typedef unsigned int u32;

constexpr int D = 64;
constexpr int K = 1024;
constexpr int NPTS = 65536;
constexpr long QOFF = (long)NPTS * D;  // 4194304
constexpr float BIAS = 24.0f;
constexpr float GATE = 5e-3f;  // r5-proven for bf16 split + pack err
constexpr int GRID = 512;      // 128 points/block

// ws layout:
constexpr size_t OFF_LOSS = 0;                            // double
constexpr size_t OFF_DONE = 8;                            // int
constexpr size_t OFF_CNT  = 16;                           // int[1024]
constexpr size_t WS_ZERO  = 4112;                         // loss+done+counts
constexpr size_t OFF_EC   = 4352;                         // float[1024] ref-order norms
constexpr size_t OFF_ECB  = 8448;                         // float[1024] norms + BIAS
constexpr size_t OFF_ET   = 12544;                        // float[1024*64] E^T [k][d]
constexpr size_t OFF_H2   = OFF_ET + (size_t)K * D * 4;   // u16[1024*64] bf16 hi of -2E
constexpr size_t OFF_L2   = OFF_H2 + (size_t)K * D * 2;   // u16[1024*64] bf16 lo

__device__ __forceinline__ float med3(float a, float b, float c) {
  return __builtin_amdgcn_fmed3f(a, b, c);
}
__device__ __forceinline__ u16 bf16rtn(float x) {
  u32 u = __float_as_uint(x);
  return (u16)((u + 0x7fffu + ((u >> 16) & 1u)) >> 16);
}
__device__ __forceinline__ float bf2f(u16 h) {
  return __uint_as_float(((u32)h) << 16);
}

// Fused prep: ref-order norms + fp32 transpose + bf16 hi/lo split of -2E.
__global__ __launch_bounds__(256) void prep(const float* __restrict__ E,
                                            float* __restrict__ eC,
                                            float* __restrict__ eCb,
                                            float* __restrict__ Et,
                                            u16* __restrict__ h2,
                                            u16* __restrict__ l2) {
  const int gid = blockIdx.x * 256 + threadIdx.x;  // 16384 threads
  const int d = gid >> 8;
  const int k0 = (gid & 255) * 4;
  float4 v = *(const float4*)&E[d * K + k0];  // coalesced
#pragma unroll
  for (int i = 0; i < 4; ++i) {
    int k = k0 + i;
    float e = (i == 0) ? v.x : (i == 1) ? v.y : (i == 2) ? v.z : v.w;
    Et[(size_t)k * 64 + d] = e;
    float m2 = -2.0f * e;  // exact
    u16 h = bf16rtn(m2);
    h2[(size_t)k * 64 + d] = h;
    l2[(size_t)k * 64 + d] = bf16rtn(m2 - bf2f(h));
  }
  if (gid < K) {
    // np.sum(E**2, axis=0) order: sequential fp32 over d ascending (r3-proven)
    float c = __fmul_rn(E[gid], E[gid]);
#pragma unroll
    for (int dd = 1; dd < D; ++dd) {
      float e = E[dd * K + gid];
      c = __fadd_rn(c, __fmul_rn(e, e));
    }
    eC[gid] = c;
    eCb[gid] = c + BIAS;
  }
}

__global__ __launch_bounds__(256) void vq_main(const float* __restrict__ x,
                                               const u16* __restrict__ h2g,
                                               const u16* __restrict__ l2g,
                                               const float* __restrict__ eC,
                                               const float* __restrict__ eCbG,
                                               const float* __restrict__ Etg,
                                               float* __restrict__ out,
                                               double* __restrict__ lossSum,
                                               int* __restrict__ counts,
                                               int* __restrict__ done) {
  // LDS: E chunk (128 codes) hi/lo, row stride 72 u16 (2-way-free banks).
  __shared__ __align__(16) u16 hA[128 * 72];
  __shared__ __align__(16) u16 lA[128 * 72];
  __shared__ __align__(16) float ecb[128];
  __shared__ __align__(16) float topbuf[256 * 4];
  __shared__ int bkbuf[128];
  __shared__ double shred[256];
  __shared__ int lastFlag;

  const int tid = threadIdx.x;
  const int w = tid >> 6;
  const int lane = tid & 63;
  const int col = lane & 15;     // A: code row; B: point col; C: point col
  const int quad = lane >> 4;    // k-group (A/B), row-group (C)
  const int blockBase = blockIdx.x * 128;
  const float INF = __builtin_inff();

  // ---- phase 1: load + split x into bf16 hi/lo B-fragments (registers) ----
  short8v Bh[2][2], Bl[2][2];
#pragma unroll
  for (int pt = 0; pt < 2; ++pt) {
    const float* xp = x + (size_t)(blockBase + w * 32 + pt * 16 + col) * 64;
#pragma unroll
    for (int s = 0; s < 2; ++s) {
      const float4* src = (const float4*)(xp + s * 32 + quad * 8);
      float4 a = src[0], b = src[1];
      float xs[8] = {a.x, a.y, a.z, a.w, b.x, b.y, b.z, b.w};
      short8v hf, lf;
#pragma unroll
      for (int j = 0; j < 8; ++j) {
        u16 h = bf16rtn(xs[j]);
        hf[j] = (short)h;
        lf[j] = (short)bf16rtn(xs[j] - bf2f(h));
      }
      Bh[pt][s] = hf;
      Bl[pt][s] = lf;
    }
  }

  // running top-2 of packed biased distances, per point-tile
  float b1[2] = {INF, INF}, b2[2] = {INF, INF};

  // ---- phase 2: K loop, 8 chunks of 128 codes (r5 core, verbatim) ----
  for (int ch = 0; ch < 8; ++ch) {
    const int kbase = ch * 128;
    __syncthreads();
#pragma unroll
    for (int i = 0; i < 4; ++i) {
      int idx = tid + i * 256;  // 1024 x 16B per split
      int k = idx >> 3, dg = idx & 7;
      *(float4*)&hA[k * 72 + dg * 8] =
          *(const float4*)&h2g[(size_t)(kbase + k) * 64 + dg * 8];
      *(float4*)&lA[k * 72 + dg * 8] =
          *(const float4*)&l2g[(size_t)(kbase + k) * 64 + dg * 8];
    }
    if (tid < 32) *(float4*)&ecb[tid * 4] = *(const float4*)&eCbG[kbase + tid * 4];
    __syncthreads();

#pragma unroll
    for (int ct = 0; ct < 8; ++ct) {  // 8 code-tiles of 16
      const int rowbase = (ct * 16 + col) * 72;
      short8v Ah0 = *(const short8v*)&hA[rowbase + quad * 8];
      short8v Ah1 = *(const short8v*)&hA[rowbase + 32 + quad * 8];
      short8v Al0 = *(const short8v*)&lA[rowbase + quad * 8];
      short8v Al1 = *(const short8v*)&lA[rowbase + 32 + quad * 8];
      float4v Ci = *(const float4v*)&ecb[ct * 16 + quad * 4];
#pragma unroll
      for (int pt = 0; pt < 2; ++pt) {
        float4v C = Ci;
        C = __builtin_amdgcn_mfma_f32_16x16x32_bf16(Ah0, Bh[pt][0], C, 0, 0, 0);
        C = __builtin_amdgcn_mfma_f32_16x16x32_bf16(Ah1, Bh[pt][1], C, 0, 0, 0);
        C = __builtin_amdgcn_mfma_f32_16x16x32_bf16(Al0, Bh[pt][0], C, 0, 0, 0);
        C = __builtin_amdgcn_mfma_f32_16x16x32_bf16(Al1, Bh[pt][1], C, 0, 0, 0);
        C = __builtin_amdgcn_mfma_f32_16x16x32_bf16(Ah0, Bl[pt][0], C, 0, 0, 0);
        C = __builtin_amdgcn_mfma_f32_16x16x32_bf16(Ah1, Bl[pt][1], C, 0, 0, 0);
#pragma unroll
        for (int r = 0; r < 4; ++r) {
          // pack local id (ch:3b | ct:3b | r:2b) into low 8 mantissa bits
          u32 u = (__float_as_uint(C[r]) & 0xffffff00u) |
                  (u32)(ch * 32 + ct * 4 + r);
          float v = __uint_as_float(u);
          float pb = b1[pt];
          b1[pt] = fminf(pb, v);
          b2[pt] = med3(pb, b2[pt], v);
        }
      }
    }
  }

  // ---- phase 3: stash per-lane top-2, merge per point, gate + refine ----
  topbuf[tid * 4 + 0] = b1[0];
  topbuf[tid * 4 + 1] = b2[0];
  topbuf[tid * 4 + 2] = b1[1];
  topbuf[tid * 4 + 3] = b2[1];
  __syncthreads();

  if (tid < 128) {  // one thread per point
    const int mw = tid >> 5, mpt = (tid >> 4) & 1, mcol = tid & 15;
    float cv[8];
    int cq[8];
    float mv0 = INF, mv1 = INF;
    int q0 = 0;
#pragma unroll
    for (int q = 0; q < 4; ++q) {
      int lbase = (mw * 64 + q * 16 + mcol) * 4 + mpt * 2;
#pragma unroll
      for (int j = 0; j < 2; ++j) {
        float v = topbuf[lbase + j];
        cv[q * 2 + j] = v;
        cq[q * 2 + j] = q;
        if (v < mv0) { mv1 = mv0; mv0 = v; q0 = q; }
        else if (v < mv1) { mv1 = v; }
      }
    }
    u32 lb = __float_as_uint(mv0) & 255u;
    int bestk = (int)((lb >> 5) * 128 + ((lb >> 2) & 7) * 16 + q0 * 4 + (lb & 3));

    if (mv1 - mv0 < GATE) {
      // ----- exact emulation of the np reference's fp32 arithmetic -----
      const float4* fx = (const float4*)(x + (size_t)(blockBase + tid) * 64);
      float fr[64];
#pragma unroll
      for (int i = 0; i < 16; ++i) {
        float4 v = fx[i];
        fr[4 * i + 0] = v.x; fr[4 * i + 1] = v.y;
        fr[4 * i + 2] = v.z; fr[4 * i + 3] = v.w;
      }
      // A = np.sum(f**2) (pairwise-8 pattern)
      float r8[8];
#pragma unroll
      for (int j = 0; j < 8; ++j) r8[j] = __fmul_rn(fr[j], fr[j]);
#pragma unroll
      for (int i = 8; i < D; i += 8)
#pragma unroll
        for (int j = 0; j < 8; ++j)
          r8[j] = __fadd_rn(r8[j], __fmul_rn(fr[i + j], fr[i + j]));
      float A = __fadd_rn(__fadd_rn(__fadd_rn(r8[0], r8[1]), __fadd_rn(r8[2], r8[3])),
                          __fadd_rn(__fadd_rn(r8[4], r8[5]), __fadd_rn(r8[6], r8[7])));

      float bd = INF;
      int bkk = K;
#pragma unroll
      for (int c = 0; c < 8; ++c) {
        u32 cb = __float_as_uint(cv[c]) & 255u;
        int k = (int)((cb >> 5) * 128 + ((cb >> 2) & 7) * 16 + cq[c] * 4 + (cb & 3));
        // M: sequential fp32 fma over d ascending — Et row is contiguous and
        // bit-identical to E's column; same fma order as the BLAS k-loop.
        const float4* er = (const float4*)(Etg + (size_t)k * 64);
        float m = 0.f;
#pragma unroll
        for (int i = 0; i < 16; ++i) {
          float4 e = er[i];
          m = __fmaf_rn(fr[4 * i + 0], e.x, m);
          m = __fmaf_rn(fr[4 * i + 1], e.y, m);
          m = __fmaf_rn(fr[4 * i + 2], e.z, m);
          m = __fmaf_rn(fr[4 * i + 3], e.w, m);
        }
        float dist = __fadd_rn(__fsub_rn(A, __fmul_rn(2.f, m)), eC[k]);
        bool better = (dist < bd) || (dist == bd && k < bkk);
        bd = better ? dist : bd;
        bkk = better ? k : bkk;
      }
      bestk = bkk;
    }

    bkbuf[tid] = bestk;
    out[QOFF + 2 + blockBase + tid] = (float)bestk;  // index (exact as float)
    atomicAdd(&counts[bestk], 1);
  }
  __syncthreads();

  // ---- phase 4: quantized write (gather from Et, coalesced) + loss ----
  const int pp = tid >> 1, half = tid & 1;
  const int bk = bkbuf[pp];
  const float4* et = (const float4*)(Etg + (size_t)bk * 64 + half * 32);
  const float4* xr = (const float4*)(x + (size_t)(blockBase + pp) * 64 + half * 32);
  float4* ov = (float4*)(out + (size_t)(blockBase + pp) * 64 + half * 32);
  float errs = 0.f;
#pragma unroll
  for (int i = 0; i < 8; ++i) {
    float4 qv = et[i];
    float4 xv = xr[i];
    float dx;
    dx = qv.x - xv.x; errs = fmaf(dx, dx, errs);
    dx = qv.y - xv.y; errs = fmaf(dx, dx, errs);
    dx = qv.z - xv.z; errs = fmaf(dx, dx, errs);
    dx = qv.w - xv.w; errs = fmaf(dx, dx, errs);
    ov[i] = qv;
  }
  double de = (double)errs;
#pragma unroll
  for (int off = 32; off > 0; off >>= 1) de += __shfl_down(de, off, 64);
  if (lane == 0) atomicAdd(lossSum, de);

  // ---- phase 5: last block finalizes loss + perplexity (r8-proven; no
  // threadfence — counts/lossSum are device-scope atomics, RELEASE on done
  // orders them before the last block's ACQUIRE) ----
  __syncthreads();
  if (tid == 0) {
    int old = __hip_atomic_fetch_add(done, 1, __ATOMIC_ACQ_REL,
                                     __HIP_MEMORY_SCOPE_AGENT);
    lastFlag = (old == GRID - 1);
  }
  __syncthreads();
  if (lastFlag) {
    double ent = 0.0;
    for (int k = tid; k < K; k += 256) {
      int c = __hip_atomic_load(&counts[k], __ATOMIC_RELAXED,
                                __HIP_MEMORY_SCOPE_AGENT);
      double pp2 = (double)c / (double)NPTS;
      ent += pp2 * log(pp2 + 1e-10);
    }
    shred[tid] = ent;
    __syncthreads();
    for (int s = 128; s > 0; s >>= 1) {
      if (tid < s) shred[tid] += shred[tid + s];
      __syncthreads();
    }
    if (tid == 0) {
      double ls = __hip_atomic_load(lossSum, __ATOMIC_RELAXED,
                                    __HIP_MEMORY_SCOPE_AGENT);
      // loss = q_latent + 0.25 * e_latent = 1.25 * mean((q - x)^2)
      out[QOFF + 0] = (float)(1.25 * ls / (double)((long)NPTS * D));
      out[QOFF + 1] = (float)exp(-shred[0]);  // perplexity
    }
  }
}

extern "C" void kernel_launch(void* const* d_in, const int* in_sizes, int n_in,
                              void* d_out, int out_size, void* d_ws, size_t ws_size,
                              hipStream_t stream) {
  const float* x = (const float*)d_in[0];
  const float* E = (const float*)d_in[1];
  float* out = (float*)d_out;

  char* ws = (char*)d_ws;
  double* lossSum = (double*)(ws + OFF_LOSS);
  int* done = (int*)(ws + OFF_DONE);
  int* counts = (int*)(ws + OFF_CNT);
  float* eC = (float*)(ws + OFF_EC);
  float* eCb = (float*)(ws + OFF_ECB);
  float* Etg = (float*)(ws + OFF_ET);
  u16* h2g = (u16*)(ws + OFF_H2);
  u16* l2g = (u16*)(ws + OFF_L2);

  // ws is poisoned 0xAA before every timed launch — zero accumulators.
  hipMemsetAsync(d_ws, 0, WS_ZERO, stream);

  prep<<<64, 256, 0, stream>>>(E, eC, eCb, Etg, h2g, l2g);
  vq_main<<<GRID, 256, 0, stream>>>(x, h2g, l2g, eC, eCb, Etg, out, lossSum,
                                    counts, done);
}